// Round 1
// baseline (180.544 us; speedup 1.0000x reference)
//
#include <hip/hip_runtime.h>
#include <hip/hip_bf16.h>
#include <cmath>

using short8 = __attribute__((ext_vector_type(8))) short;
using f32x4  = __attribute__((ext_vector_type(4))) float;

#define DEV static __device__ __forceinline__

DEV unsigned short f2bf(float f) {
  union { float f; unsigned u; } v; v.f = f;
  unsigned r = v.u + 0x7FFFu + ((v.u >> 16) & 1u);
  return (unsigned short)(r >> 16);
}
DEV float bf2f(unsigned short b) {
  union { unsigned u; float f; } v; v.u = ((unsigned)b) << 16;
  return v.f;
}

DEV void async_copy16(const void* g, void* l) {
  __builtin_amdgcn_global_load_lds(
      (const __attribute__((address_space(1))) void*)g,
      (__attribute__((address_space(3))) void*)l, 16, 0, 0);
}

// ---------------- f32 -> bf16 convert (vector x4) ----------------
__global__ __launch_bounds__(256) void cvt_bf16_kernel(
    const float* __restrict__ src, unsigned short* __restrict__ dst, int n4) {
  int i = blockIdx.x * 256 + threadIdx.x;
  if (i >= n4) return;
  float4 v = ((const float4*)src)[i];
  ushort4 o;
  o.x = f2bf(v.x); o.y = f2bf(v.y); o.z = f2bf(v.z); o.w = f2bf(v.w);
  ((ushort4*)dst)[i] = o;
}

// ---------------- pack bq|bk|bv ----------------
__global__ __launch_bounds__(256) void pack_bias_kernel(
    const float* __restrict__ bq, const float* __restrict__ bk,
    const float* __restrict__ bv, float* __restrict__ dst) {
  int i = blockIdx.x * 256 + threadIdx.x;
  if (i >= 3072) return;
  const float* s = (i < 1024) ? bq : (i < 2048) ? bk : bv;
  dst[i] = s[i & 1023];
}

// ---------------- sinusoidal rel-pos table (1024 rows incl. pad row) -------
__global__ __launch_bounds__(256) void pe_kernel(unsigned short* __restrict__ pe) {
  int idx = blockIdx.x * 256 + threadIdx.x;  // 1024*512 threads
  int r = idx >> 9;
  int m = idx & 511;
  // inv_freq = 10000^(-2m/1024) = exp(-m * ln(10000)/512)
  double inv_freq = exp((double)m * -0.017988946039016004);
  double ang = (double)(511 - r) * inv_freq;
  pe[(size_t)r * 1024 + 2 * m]     = f2bf((float)sin(ang));
  pe[(size_t)r * 1024 + 2 * m + 1] = f2bf((float)cos(ang));
}

// ---------------- GEMM: C[M,N] = A[M,K] @ B[N,K]^T + bias[N] ----------------
// A,B bf16 row-major; C bf16 or f32 row-major. 128x128 tile, BK=64, 4 waves.
// LDS rows are 128B; XOR-swizzle byte^=((row&7)<<4), source-side pre-swizzled
// for global_load_lds (rule #21).
template <int OUTF32>
__global__ __launch_bounds__(256) void gemm_bt_kernel(
    const unsigned short* __restrict__ A, const unsigned short* __restrict__ B,
    const float* __restrict__ bias, void* __restrict__ Cout,
    int M, int N, int K) {
  __shared__ unsigned short sA[128 * 64];
  __shared__ unsigned short sB[128 * 64];
  const int tid = threadIdx.x;
  const int lane = tid & 63;
  const int wave = tid >> 6;
  const int ntiles = N >> 7;
  const int mt = blockIdx.x / ntiles;
  const int nt = blockIdx.x - mt * ntiles;
  const int m0 = mt << 7, n0 = nt << 7;

  const unsigned short* gA[4];
  const unsigned short* gB[4];
  unsigned ldst[4];
#pragma unroll
  for (int it = 0; it < 4; ++it) {
    unsigned o = (unsigned)(it * 4096 + wave * 1024 + lane * 16);
    unsigned row = o >> 7;
    unsigned x = (o & 127u) ^ ((row & 7u) << 4);
    ldst[it] = it * 4096 + wave * 1024;
    gA[it] = A + (size_t)(m0 + (int)row) * K + (x >> 1);
    gB[it] = B + (size_t)(n0 + (int)row) * K + (x >> 1);
  }

  f32x4 acc[4][4];
#pragma unroll
  for (int i = 0; i < 4; ++i)
#pragma unroll
    for (int j = 0; j < 4; ++j) acc[i][j] = f32x4{0.f, 0.f, 0.f, 0.f};

  const int wm = (wave >> 1) << 6;
  const int wn = (wave & 1) << 6;
  const int rsel = lane & 15;
  const int ksel = (lane >> 4) << 4;

  for (int k0 = 0; k0 < K; k0 += 64) {
#pragma unroll
    for (int it = 0; it < 4; ++it) {
      async_copy16(gA[it] + k0, (char*)sA + ldst[it]);
      async_copy16(gB[it] + k0, (char*)sB + ldst[it]);
    }
    __syncthreads();
#pragma unroll
    for (int kb = 0; kb < 2; ++kb) {
      const int kbyte = kb * 64 + ksel;
      short8 af[4], bf8[4];
#pragma unroll
      for (int i = 0; i < 4; ++i) {
        const int ra = wm + i * 16 + rsel;
        af[i] = *(const short8*)((const char*)sA + ra * 128 + (kbyte ^ ((ra & 7) << 4)));
        const int rb = wn + i * 16 + rsel;
        bf8[i] = *(const short8*)((const char*)sB + rb * 128 + (kbyte ^ ((rb & 7) << 4)));
      }
#pragma unroll
      for (int i = 0; i < 4; ++i)
#pragma unroll
        for (int j = 0; j < 4; ++j)
          acc[i][j] = __builtin_amdgcn_mfma_f32_16x16x32_bf16(af[i], bf8[j], acc[i][j], 0, 0, 0);
    }
    __syncthreads();
  }

#pragma unroll
  for (int i = 0; i < 4; ++i) {
    const int row0 = m0 + wm + i * 16 + ((lane >> 4) << 2);
#pragma unroll
    for (int j = 0; j < 4; ++j) {
      const int col = n0 + wn + j * 16 + rsel;
      const float bb = bias[col];
#pragma unroll
      for (int r = 0; r < 4; ++r) {
        const float val = acc[i][j][r] + bb;
        if (OUTF32)
          ((float*)Cout)[(size_t)(row0 + r) * N + col] = val;
        else
          ((unsigned short*)Cout)[(size_t)(row0 + r) * N + col] = f2bf(val);
      }
    }
  }
}

// ---------------- fused rel-pos flash attention ----------------
// grid: (b*16 + h)*8 + qtile ; 256 thr = 4 waves, 16 q-rows/wave, KVBLK=64.
// SE[q,k] = Qv[q] . E[511+k-q]  (skew identity); per-tile E window is 128 rows,
// per-wave G-band is 5 col-fragments starting at c0w = 48-16*wave.
__global__ __launch_bounds__(256) void attn_kernel(
    const unsigned short* __restrict__ QKV,  // (4096, 3072): Q|K|V
    const unsigned short* __restrict__ E,    // (1024, 1024)
    const float* __restrict__ uvec, const float* __restrict__ vvec,
    unsigned short* __restrict__ O) {        // (4096, 1024)
  __shared__ unsigned short sQu[64 * 64];
  __shared__ unsigned short sQv[64 * 64];
  __shared__ unsigned short sK[64 * 64];
  __shared__ unsigned short sVt[64 * 64];
  __shared__ unsigned short sE[128 * 64];
  __shared__ unsigned short sP[4][16 * 64];
  __shared__ unsigned short sG[4][16 * 128];

  const int tid = threadIdx.x;
  const int lane = tid & 63;
  const int wave = tid >> 6;
  const int bid = blockIdx.x;
  const int qt = bid & 7;
  const int h = (bid >> 3) & 15;
  const int b = bid >> 7;
  const int q0 = qt << 6;

  const unsigned short* Qb = QKV + (size_t)b * 512 * 3072 + h * 64;
  const unsigned short* Kb = Qb + 1024;
  const unsigned short* Vb = Qb + 2048;

  // stage Qu = Q+u, Qv = Q+v (swizzled rows)
#pragma unroll
  for (int it = 0; it < 2; ++it) {
    const int c = it * 256 + tid;
    const int row = c >> 3;
    const int cb = (c & 7) << 3;
    short8 q8 = *(const short8*)(Qb + (size_t)(q0 + row) * 3072 + cb);
    short8 u8, v8;
#pragma unroll
    for (int j = 0; j < 8; ++j) {
      const float qf = bf2f((unsigned short)q8[j]);
      u8[j] = (short)f2bf(qf + uvec[h * 64 + cb + j]);
      v8[j] = (short)f2bf(qf + vvec[h * 64 + cb + j]);
    }
    const int byt = row * 128 + (((c & 7) << 4) ^ ((row & 7) << 4));
    *(short8*)((char*)sQu + byt) = u8;
    *(short8*)((char*)sQv + byt) = v8;
  }

  float mrun[4], lrun[4];
  f32x4 oacc[4];
#pragma unroll
  for (int r = 0; r < 4; ++r) { mrun[r] = -INFINITY; lrun[r] = 0.f; }
#pragma unroll
  for (int n = 0; n < 4; ++n) oacc[n] = f32x4{0.f, 0.f, 0.f, 0.f};

  const int c0w = 48 - wave * 16;
  const int rsel = lane & 15;
  const int ksel = (lane >> 4) << 4;
  const int ilocb = (lane >> 4) << 2;

  for (int kt = 0; kt < 8; ++kt) {
    const int k0 = kt << 6;
    const int rbase = 448 + k0 - q0;  // E-window base row, always in [0,896]

    // K tile via global_load_lds (source pre-swizzled)
#pragma unroll
    for (int it = 0; it < 2; ++it) {
      const unsigned o = (unsigned)(it * 4096 + wave * 1024 + lane * 16);
      const unsigned row = o >> 7;
      const unsigned x = (o & 127u) ^ ((row & 7u) << 4);
      async_copy16(Kb + (size_t)(k0 + (int)row) * 3072 + (x >> 1),
                   (char*)sK + it * 4096 + wave * 1024);
    }
    // E window (128 rows)
#pragma unroll
    for (int it = 0; it < 4; ++it) {
      const unsigned o = (unsigned)(it * 4096 + wave * 1024 + lane * 16);
      const unsigned row = o >> 7;
      const unsigned x = (o & 127u) ^ ((row & 7u) << 4);
      async_copy16(E + (size_t)(rbase + (int)row) * 1024 + h * 64 + (x >> 1),
                   (char*)sE + it * 4096 + wave * 1024);
    }
    // V transposed (reg-staged scalar writes)
#pragma unroll
    for (int it = 0; it < 2; ++it) {
      const int c = it * 256 + tid;
      const int trow = c >> 3;
      const int db = (c & 7) << 3;
      short8 v8 = *(const short8*)(Vb + (size_t)(k0 + trow) * 3072 + db);
#pragma unroll
      for (int j = 0; j < 8; ++j) {
        const int d = db + j;
        *(unsigned short*)((char*)sVt + d * 128 + ((trow * 2) ^ ((d & 7) << 4))) =
            (unsigned short)v8[j];
      }
    }
    __syncthreads();

    // Qu/Qv A-fragments for this wave's 16 rows
    short8 aU[2], aV[2];
#pragma unroll
    for (int kb = 0; kb < 2; ++kb) {
      const int ra = wave * 16 + rsel;
      const int off = ra * 128 + ((kb * 64 + ksel) ^ ((ra & 7) << 4));
      aU[kb] = *(const short8*)((const char*)sQu + off);
      aV[kb] = *(const short8*)((const char*)sQv + off);
    }

    // SK = Qu @ K^T  (16 x 64)
    f32x4 skacc[4];
#pragma unroll
    for (int nf = 0; nf < 4; ++nf) skacc[nf] = f32x4{0.f, 0.f, 0.f, 0.f};
#pragma unroll
    for (int nf = 0; nf < 4; ++nf)
#pragma unroll
      for (int kb = 0; kb < 2; ++kb) {
        const int rb = nf * 16 + rsel;
        short8 b8 = *(const short8*)((const char*)sK + rb * 128 +
                                     ((kb * 64 + ksel) ^ ((rb & 7) << 4)));
        skacc[nf] = __builtin_amdgcn_mfma_f32_16x16x32_bf16(aU[kb], b8, skacc[nf], 0, 0, 0);
      }

    // G = Qv @ Ewin^T (16 x 80 band)
    f32x4 gacc[5];
#pragma unroll
    for (int cf = 0; cf < 5; ++cf) gacc[cf] = f32x4{0.f, 0.f, 0.f, 0.f};
#pragma unroll
    for (int cf = 0; cf < 5; ++cf)
#pragma unroll
      for (int kb = 0; kb < 2; ++kb) {
        const int rb = c0w + cf * 16 + rsel;
        short8 e8 = *(const short8*)((const char*)sE + rb * 128 +
                                     ((kb * 64 + ksel) ^ ((rb & 7) << 4)));
        gacc[cf] = __builtin_amdgcn_mfma_f32_16x16x32_bf16(aV[kb], e8, gacc[cf], 0, 0, 0);
      }
#pragma unroll
    for (int cf = 0; cf < 5; ++cf)
#pragma unroll
      for (int r = 0; r < 4; ++r)
        sG[wave][(ilocb + r) * 128 + c0w + cf * 16 + rsel] = f2bf(gacc[cf][r]);

    // S = (SK + diag-gather(G)) * 1/sqrt(64); online softmax
    float sv[4][4];
#pragma unroll
    for (int nf = 0; nf < 4; ++nf)
#pragma unroll
      for (int r = 0; r < 4; ++r) {
        const int iloc = ilocb + r;
        const int c = c0w + 15 - iloc + nf * 16 + rsel;  // 63 - i + j
        sv[nf][r] = (skacc[nf][r] + bf2f(sG[wave][iloc * 128 + c])) * 0.125f;
      }

    float scl[4], rsum[4];
#pragma unroll
    for (int r = 0; r < 4; ++r) {
      float t = fmaxf(fmaxf(sv[0][r], sv[1][r]), fmaxf(sv[2][r], sv[3][r]));
      t = fmaxf(t, __shfl_xor(t, 1, 64));
      t = fmaxf(t, __shfl_xor(t, 2, 64));
      t = fmaxf(t, __shfl_xor(t, 4, 64));
      t = fmaxf(t, __shfl_xor(t, 8, 64));
      const float mnew = fmaxf(mrun[r], t);
      scl[r] = __expf(mrun[r] - mnew);
      mrun[r] = mnew;
      rsum[r] = 0.f;
    }

#pragma unroll
    for (int nf = 0; nf < 4; ++nf)
#pragma unroll
      for (int r = 0; r < 4; ++r) {
        const float p = __expf(sv[nf][r] - mrun[r]);
        rsum[r] += p;
        const int iloc = ilocb + r;
        const int jb = (nf * 16 + rsel) * 2;
        *(unsigned short*)((char*)sP[wave] + iloc * 128 + (jb ^ ((iloc & 7) << 4))) = f2bf(p);
      }

#pragma unroll
    for (int r = 0; r < 4; ++r) {
      float s = rsum[r];
      s += __shfl_xor(s, 1, 64);
      s += __shfl_xor(s, 2, 64);
      s += __shfl_xor(s, 4, 64);
      s += __shfl_xor(s, 8, 64);
      lrun[r] = lrun[r] * scl[r] + s;
    }
#pragma unroll
    for (int nf = 0; nf < 4; ++nf)
#pragma unroll
      for (int r = 0; r < 4; ++r) oacc[nf][r] *= scl[r];

    // O += P @ V
#pragma unroll
    for (int kb = 0; kb < 2; ++kb) {
      const int kbyte = kb * 64 + ksel;
      short8 ap = *(const short8*)((const char*)sP[wave] + rsel * 128 +
                                   (kbyte ^ ((rsel & 7) << 4)));
#pragma unroll
      for (int nf = 0; nf < 4; ++nf) {
        const int rv = nf * 16 + rsel;
        short8 v8 = *(const short8*)((const char*)sVt + rv * 128 +
                                     (kbyte ^ ((rv & 7) << 4)));
        oacc[nf] = __builtin_amdgcn_mfma_f32_16x16x32_bf16(ap, v8, oacc[nf], 0, 0, 0);
      }
    }
    __syncthreads();
  }

#pragma unroll
  for (int nf = 0; nf < 4; ++nf)
#pragma unroll
    for (int r = 0; r < 4; ++r) {
      const int t = q0 + wave * 16 + ilocb + r;
      const int col = h * 64 + nf * 16 + rsel;
      O[(size_t)(b * 512 + t) * 1024 + col] = f2bf(oacc[nf][r] / lrun[r]);
    }
}

// ---------------- launch ----------------
extern "C" void kernel_launch(void* const* d_in, const int* in_sizes, int n_in,
                              void* d_out, int out_size, void* d_ws, size_t ws_size,
                              hipStream_t stream) {
  const float* x  = (const float*)d_in[0];
  const float* Wq = (const float*)d_in[1];
  const float* bq = (const float*)d_in[2];
  const float* Wk = (const float*)d_in[3];
  const float* bk = (const float*)d_in[4];
  const float* Wv = (const float*)d_in[5];
  const float* bv = (const float*)d_in[6];
  const float* Wp = (const float*)d_in[7];
  const float* bp = (const float*)d_in[8];
  const float* Wo = (const float*)d_in[9];
  const float* bo = (const float*)d_in[10];
  const float* u  = (const float*)d_in[11];
  const float* v  = (const float*)d_in[12];
  float* out = (float*)d_out;

  char* ws = (char*)d_ws;
  const size_t MB = 1024 * 1024;
  unsigned short* xb    = (unsigned short*)(ws);             // 4096x1024 bf16
  unsigned short* Wqkvb = (unsigned short*)(ws + 8 * MB);    // 3072x1024
  unsigned short* Wpb   = (unsigned short*)(ws + 14 * MB);   // 1024x1024
  unsigned short* Wob   = (unsigned short*)(ws + 16 * MB);   // 1024x1024
  unsigned short* peb   = (unsigned short*)(ws + 18 * MB);   // 1024x1024
  unsigned short* QKVb  = (unsigned short*)(ws + 20 * MB);   // 4096x3072
  unsigned short* Eb    = (unsigned short*)(ws + 44 * MB);   // 1024x1024
  unsigned short* Ob    = (unsigned short*)(ws + 46 * MB);   // 4096x1024
  float* bqkv           = (float*)(ws + 54 * MB);            // 3072 f32

  cvt_bf16_kernel<<<dim3(4096), dim3(256), 0, stream>>>(x, xb, 1048576);
  cvt_bf16_kernel<<<dim3(1024), dim3(256), 0, stream>>>(Wq, Wqkvb, 262144);
  cvt_bf16_kernel<<<dim3(1024), dim3(256), 0, stream>>>(Wk, Wqkvb + 1048576, 262144);
  cvt_bf16_kernel<<<dim3(1024), dim3(256), 0, stream>>>(Wv, Wqkvb + 2097152, 262144);
  cvt_bf16_kernel<<<dim3(1024), dim3(256), 0, stream>>>(Wp, Wpb, 262144);
  cvt_bf16_kernel<<<dim3(1024), dim3(256), 0, stream>>>(Wo, Wob, 262144);
  pack_bias_kernel<<<dim3(12), dim3(256), 0, stream>>>(bq, bk, bv, bqkv);
  pe_kernel<<<dim3(2048), dim3(256), 0, stream>>>(peb);

  gemm_bt_kernel<0><<<dim3(32 * 24), dim3(256), 0, stream>>>(xb, Wqkvb, bqkv, QKVb, 4096, 3072, 1024);
  gemm_bt_kernel<0><<<dim3(8 * 8), dim3(256), 0, stream>>>(peb, Wpb, bp, Eb, 1024, 1024, 1024);
  attn_kernel<<<dim3(1024), dim3(256), 0, stream>>>(QKVb, Eb, u, v, Ob);
  gemm_bt_kernel<1><<<dim3(32 * 8), dim3(256), 0, stream>>>(Ob, Wob, bo, out, 4096, 1024, 1024);
}